// Round 6
// baseline (196.670 us; speedup 1.0000x reference)
//
#include <hip/hip_runtime.h>

#define NN 100000
#define NE 1600000
#define FIN 64
#define FOUT 7

#define BSH 9                        // bucket = dst >> 9 (512 nodes)
#define NBK 196                      // ceil(100000/512)
#define PBLK 2000                    // partition blocks (2000*800 = NE exact)
#define PTH  256
#define EPB  800                     // edges per partition region
#define NCOPY 4                      // per-wave counter copies (4 waves)
#define NCTR (NBK * NCOPY)           // 784
#define ROWS 200                     // offs row stride in u16 (197 used)
#define SPLIT 4                      // acc blocks per bucket
#define NTASK (NBK * SPLIT)          // 784
#define RPS (PBLK / SPLIT)           // 500 regions per acc task
#define ATH 512
#define WSLOT 12                     // aligned uint4 window: 3 x dwordx4
#define FSTR 520                     // facc stride: 520%32=8 -> banks vary with j
#define PROJB 391
#define INVALID 0xFFFFFFFFu

#define FADD(p, v) __hip_atomic_fetch_add((p), (v), __ATOMIC_RELAXED, __HIP_MEMORY_SCOPE_WORKGROUP)

__device__ __forceinline__ unsigned bf16r(float f) {   // round-to-nearest-even
    unsigned u = __float_as_uint(f);
    return (u + 0x7fffu + ((u >> 16) & 1u)) >> 16;
}
__device__ __forceinline__ float bflo(unsigned u) { return __uint_as_float(u << 16); }
__device__ __forceinline__ float bfhi(unsigned u) { return __uint_as_float(u & 0xffff0000u); }

// ---------------------------------------------------------------------------
// Kernel 1: per-node projections — REVERTED to the original (cross-round
// algebra: it runs ~2us; the R5 LDS-staged version was ~16us slower).
// ---------------------------------------------------------------------------
__global__ __launch_bounds__(256) void proj_kernel(
    const float* __restrict__ x, const float* __restrict__ Wl,
    const float* __restrict__ bl, const float* __restrict__ Wr,
    unsigned* __restrict__ z, float* __restrict__ outself, int n)
{
    int i = blockIdx.x * blockDim.x + threadIdx.x;
    if (i >= n) return;

    float al[FOUT], ar[FOUT];
#pragma unroll
    for (int j = 0; j < FOUT; ++j) { al[j] = 0.f; ar[j] = 0.f; }

    const float4* xr = (const float4*)(x + (size_t)i * FIN);
#pragma unroll
    for (int kk = 0; kk < FIN / 4; ++kk) {
        float4 xv = xr[kk];
        float v[4] = {xv.x, xv.y, xv.z, xv.w};
#pragma unroll
        for (int c = 0; c < 4; ++c) {
            int k = kk * 4 + c;
#pragma unroll
            for (int j = 0; j < FOUT; ++j) {
                al[j] = fmaf(v[c], Wl[k * FOUT + j], al[j]);   // uniform -> s_load
                ar[j] = fmaf(v[c], Wr[k * FOUT + j], ar[j]);
            }
        }
    }

    uint4 pk;
    pk.x = bf16r(al[0]) | (bf16r(al[1]) << 16);
    pk.y = bf16r(al[2]) | (bf16r(al[3]) << 16);
    pk.z = bf16r(al[4]) | (bf16r(al[5]) << 16);
    pk.w = bf16r(al[6]);
    ((uint4*)z)[i] = pk;

    float* o = outself + (size_t)i * FOUT;
#pragma unroll
    for (int j = 0; j < FOUT; ++j)
        o[j] = ar[j] + bl[j];
}

// ---------------------------------------------------------------------------
// Kernel 2: partition (unchanged from the 120.7us baseline).
// ---------------------------------------------------------------------------
__global__ __launch_bounds__(PTH) void part_kernel(
    const int* __restrict__ eg, unsigned* __restrict__ part,
    unsigned short* __restrict__ offs)
{
    __shared__ unsigned st_cnt[NCTR];      // copy-major: [wave][bucket]
    __shared__ unsigned st_start[NCTR];
    __shared__ unsigned stage[EPB];
    __shared__ unsigned wsum[NCOPY];

    const int t    = threadIdx.x;
    const int e0   = (int)blockIdx.x * EPB;
    const int lane = t & 63;
    const int wv   = t >> 6;

    for (int b = t; b < NCTR; b += PTH) st_cnt[b] = 0;
    __syncthreads();

    // pass A: two dwordx4 edge loads + merged hist+rank on this wave's copy
    unsigned held[4], hcr[4];
#pragma unroll
    for (int q = 0; q < 4; ++q) hcr[q] = INVALID;
    if (t < EPB / 4) {
        uint4 S = *(const uint4*)(eg + e0 + 4 * t);        // 4 srcs
        uint4 D = *(const uint4*)(eg + NE + e0 + 4 * t);   // 4 dsts
        unsigned ss[4] = {S.x, S.y, S.z, S.w};
        unsigned dd[4] = {D.x, D.y, D.z, D.w};
#pragma unroll
        for (int q = 0; q < 4; ++q) {
            unsigned b = dd[q] >> BSH;
            unsigned cidx = (unsigned)wv * NBK + b;        // copy-major
            unsigned r = atomicAdd(&st_cnt[cidx], 1u);
            held[q] = ((dd[q] & 511u) << 17) | ss[q];      // ldst 9b | src 17b
            hcr[q]  = (cidx << 10) | r;                    // cidx 10b | r<800 10b
        }
    }
    __syncthreads();

    // scan: thread t<196 owns bucket t; sum its 4 wave-copies, then a
    // 196-entry shfl scan across 4 waves for bucket starts.
    unsigned c[4], p[4], tot = 0;
    if (t < NBK) {
#pragma unroll
        for (int w = 0; w < NCOPY; ++w) c[w] = st_cnt[w * NBK + t];
        p[0] = 0; p[1] = c[0]; p[2] = c[0] + c[1]; p[3] = p[2] + c[2];
        tot = p[3] + c[3];
    }
    unsigned inc = tot;
#pragma unroll
    for (int off = 1; off < 64; off <<= 1) {
        unsigned v = (unsigned)__shfl_up((int)inc, off, 64);
        if (lane >= off) inc += v;
    }
    if (lane == 63) wsum[wv] = inc;
    __syncthreads();
    if (t == 0) {
        unsigned run = 0;
#pragma unroll
        for (int w = 0; w < NCOPY; ++w) { unsigned tmp = wsum[w]; wsum[w] = run; run += tmp; }
    }
    __syncthreads();
    unsigned bstart = wsum[wv] + inc - tot;    // exclusive bucket start
    if (t < NBK) {
        offs[(size_t)blockIdx.x * ROWS + t] = (unsigned short)bstart;
#pragma unroll
        for (int w = 0; w < NCOPY; ++w) st_start[w * NBK + t] = bstart + p[w];
    }
    if (t == NBK) offs[(size_t)blockIdx.x * ROWS + NBK] = (unsigned short)EPB;
    __syncthreads();

    // pass B: place held edges into bucket-sorted stage
#pragma unroll
    for (int q = 0; q < 4; ++q) {
        if (hcr[q] != INVALID) {
            unsigned cidx = hcr[q] >> 10, r = hcr[q] & 0x3FFu;
            stage[st_start[cidx] + r] = held[q];
        }
    }
    __syncthreads();

    // pass C: linear region dump (uint4)
    const uint4* sg = (const uint4*)stage;
    uint4* pg = (uint4*)(part + (size_t)blockIdx.x * EPB);
    for (int j = t; j < EPB / 4; j += PTH) pg[j] = sg[j];
}

// ---------------------------------------------------------------------------
// Kernel 3: accumulate — ds_add experiment, both failure hypotheses removed:
//  (a) atomics: __hip_atomic_fetch_add, relaxed, WORKGROUP scope, applied to
//      the in-scope __shared__ array -> non-returning ds_add_f32.
//  (b) latency chain: ALL 12 z-gathers issued unconditionally into registers
//      (compile-time indices) BEFORE any atomic -> no alias serialization.
//  (c) facc stride 520 (%32=8) decorrelates banks across components j.
// If this still runs ~90us, the LDS-atomic path is convicted outright and
// the sort-based acc (21.8us) returns next round.
// ---------------------------------------------------------------------------
__global__ __launch_bounds__(ATH) void acc_kernel(
    const unsigned short* __restrict__ offs, const unsigned* __restrict__ part,
    const unsigned* __restrict__ zb, float* __restrict__ partial)
{
    __shared__ float facc[8][FSTR];

    const int t  = threadIdx.x;
    const int k  = blockIdx.x >> 2;      // bucket
    const int sp = blockIdx.x & 3;       // split

    for (int idx = t; idx < 8 * FSTR; idx += ATH) ((float*)facc)[idx] = 0.f;
    __syncthreads();

    unsigned rbase = 0, len = 0;
    if (t < RPS) {
        unsigned r = (unsigned)(sp * RPS + t);
        unsigned o0 = offs[(size_t)r * ROWS + k];
        unsigned o1 = offs[(size_t)r * ROWS + k + 1];
        len   = o1 - o0;
        rbase = r * EPB + o0;
    }

    // aligned-window vector read of this thread's region slice
    unsigned sh = rbase & 3u;
    const uint4* p4 = (const uint4*)part;
    unsigned wbase = rbase >> 2;
    uint4 W0 = len ? p4[wbase]     : make_uint4(0, 0, 0, 0);
    uint4 W1 = len ? p4[wbase + 1] : make_uint4(0, 0, 0, 0);
    uint4 W2 = len ? p4[wbase + 2] : make_uint4(0, 0, 0, 0);
    unsigned win[WSLOT] = {W0.x, W0.y, W0.z, W0.w,
                           W1.x, W1.y, W1.z, W1.w,
                           W2.x, W2.y, W2.z, W2.w};
    unsigned F = min(len, WSLOT - sh);

    // phase 1: unconditional z prefetch per slot (no atomic can block these;
    // invalid slots read a neighbor's valid edge or workspace slack - safe)
    uint4    zv[WSLOT];
    unsigned nd[WSLOT];
    bool     vl[WSLOT];
#pragma unroll
    for (int q = 0; q < WSLOT; ++q) {
        unsigned uq = (unsigned)q;
        bool v = (uq >= sh) && (uq < sh + F);
        unsigned e = win[q];
        vl[q] = v;
        nd[q] = e >> 17;
        zv[q] = ((const uint4*)zb)[e & 0x1FFFFu];
    }

    // phase 2: 8 LDS float atomics per valid slot
#pragma unroll
    for (int q = 0; q < WSLOT; ++q) {
        if (vl[q]) {
            unsigned n = nd[q];
            FADD(&facc[0][n], bflo(zv[q].x));
            FADD(&facc[1][n], bfhi(zv[q].x));
            FADD(&facc[2][n], bflo(zv[q].y));
            FADD(&facc[3][n], bfhi(zv[q].y));
            FADD(&facc[4][n], bflo(zv[q].z));
            FADD(&facc[5][n], bfhi(zv[q].z));
            FADD(&facc[6][n], bflo(zv[q].w));
            FADD(&facc[7][n], 1.0f);
        }
    }
    for (unsigned j = F; j < len; ++j) {      // rare tail (len > window)
        unsigned e = part[rbase + j];
        unsigned n = e >> 17;
        uint4 zr = ((const uint4*)zb)[e & 0x1FFFFu];
        FADD(&facc[0][n], bflo(zr.x));
        FADD(&facc[1][n], bfhi(zr.x));
        FADD(&facc[2][n], bflo(zr.y));
        FADD(&facc[3][n], bfhi(zr.y));
        FADD(&facc[4][n], bflo(zr.z));
        FADD(&facc[5][n], bfhi(zr.z));
        FADD(&facc[6][n], bflo(zr.w));
        FADD(&facc[7][n], 1.0f);
    }
    __syncthreads();

    // write per-(bucket,split) partial in the same layout as before
    float* pp = partial + ((size_t)blockIdx.x * 512 + t) * 8;
    *(float4*)(pp)     = make_float4(facc[0][t], facc[1][t], facc[2][t], facc[3][t]);
    *(float4*)(pp + 4) = make_float4(facc[4][t], facc[5][t], facc[6][t], facc[7][t]);
}

// ---------------------------------------------------------------------------
// Kernel 4: merge 4 split partials + mean + self + relu (unchanged).
// ---------------------------------------------------------------------------
__global__ __launch_bounds__(256) void merge_kernel(
    const float* __restrict__ partial, float* __restrict__ out, int n)
{
    int i = blockIdx.x * blockDim.x + threadIdx.x;
    if (i >= n) return;
    int k = i >> BSH;
    int node = i & 511;

    float s0 = 0.f, s1 = 0.f, s2 = 0.f, s3 = 0.f, s4 = 0.f, s5 = 0.f, s6 = 0.f, cn = 0.f;
#pragma unroll
    for (int s = 0; s < SPLIT; ++s) {
        const float4* p = (const float4*)(partial + ((size_t)(k * SPLIT + s) * 512 + node) * 8);
        float4 a = p[0], b = p[1];
        s0 += a.x; s1 += a.y; s2 += a.z; s3 += a.w;
        s4 += b.x; s5 += b.y; s6 += b.z; cn += b.w;
    }
    float r = 1.0f / fmaxf(cn, 1.0f);
    float* o = out + (size_t)i * FOUT;
    o[0] = fmaxf(fmaf(s0, r, o[0]), 0.f);
    o[1] = fmaxf(fmaf(s1, r, o[1]), 0.f);
    o[2] = fmaxf(fmaf(s2, r, o[2]), 0.f);
    o[3] = fmaxf(fmaf(s3, r, o[3]), 0.f);
    o[4] = fmaxf(fmaf(s4, r, o[4]), 0.f);
    o[5] = fmaxf(fmaf(s5, r, o[5]), 0.f);
    o[6] = fmaxf(fmaf(s6, r, o[6]), 0.f);
}

extern "C" void kernel_launch(void* const* d_in, const int* in_sizes, int n_in,
                              void* d_out, int out_size, void* d_ws, size_t ws_size,
                              hipStream_t stream) {
    const float* x   = (const float*)d_in[0];
    const int*   edg = (const int*)d_in[1];    // harness passes integers as int32
    const float* Wl  = (const float*)d_in[2];
    const float* bl  = (const float*)d_in[3];
    const float* Wr  = (const float*)d_in[4];
    float* out = (float*)d_out;

    // ws: z 1.6 MB | part 6.4 MB (+64B window slack) | offs 0.8 MB | partial 12.9 MB
    unsigned*       z       = (unsigned*)d_ws;                            // [NN*4]
    unsigned*       part    = z + (size_t)NN * 4;                         // [NE + 16]
    unsigned short* offs    = (unsigned short*)(part + (size_t)NE + 16); // [PBLK*ROWS]
    float*          partial = (float*)(offs + (size_t)PBLK * ROWS);      // [NTASK*512*8]

    proj_kernel<<<PROJB, 256, 0, stream>>>(x, Wl, bl, Wr, z, out, NN);
    part_kernel<<<PBLK, PTH, 0, stream>>>(edg, part, offs);
    acc_kernel<<<NTASK, ATH, 0, stream>>>(offs, part, z, partial);
    merge_kernel<<<(NN + 255) / 256, 256, 0, stream>>>(partial, out, NN);
}

// Round 9
// 129.969 us; speedup vs baseline: 1.5132x; 1.5132x over previous
//
#include <hip/hip_runtime.h>

#define NN 100000
#define NE 1600000
#define FIN 64
#define FOUT 7

#define BSH 9                        // bucket = dst >> 9 (512 nodes)
#define NBK 196                      // ceil(100000/512)
#define PBLK 2000                    // partition blocks (2000*800 = NE exact)
#define PTH  256
#define EPB  800                     // edges per partition region
#define NCOPY 4                      // per-wave counter copies (4 waves)
#define NCTR (NBK * NCOPY)           // 784
#define ROWS 200                     // offs row stride in u16 (197 used)
#define SPLIT 4                      // acc blocks per bucket
#define NTASK (NBK * SPLIT)          // 784
#define RPS (PBLK / SPLIT)           // 500 regions per acc task
#define ATH 512
#define WSLOT 12                     // aligned uint4 window: 3 x dwordx4
#define OVCAP 256                    // LDS overflow pairs (expect ~4/task)
#define SCAP 3968                    // padded stage cap (edges<=2250 + align pad 1536)
#define PROJB 391
#define INVALID 0xFFFFFFFFu

__device__ __forceinline__ unsigned bf16r(float f) {   // round-to-nearest-even
    unsigned u = __float_as_uint(f);
    return (u + 0x7fffu + ((u >> 16) & 1u)) >> 16;
}
__device__ __forceinline__ float bflo(unsigned u) { return __uint_as_float(u << 16); }
__device__ __forceinline__ float bfhi(unsigned u) { return __uint_as_float(u & 0xffff0000u); }

// Wave-parallel multi-split: mask of valid lanes whose BITS-bit key == n.
// All lanes of the wave MUST execute this (ballots are convergent); the
// caller gates use of the result by v.
template <int BITS>
__device__ __forceinline__ unsigned long long matchmask(unsigned n, bool v) {
    unsigned long long m = __ballot(v ? 1 : 0);
#pragma unroll
    for (int b = 0; b < BITS; ++b) {
        unsigned long long bb = __ballot((int)((n >> b) & 1u));
        m &= ((n >> b) & 1u) ? bb : ~bb;
    }
    return m;
}

// ---------------------------------------------------------------------------
// Kernel 1: per-node projections (original fast version, unchanged).
// ---------------------------------------------------------------------------
__global__ __launch_bounds__(256) void proj_kernel(
    const float* __restrict__ x, const float* __restrict__ Wl,
    const float* __restrict__ bl, const float* __restrict__ Wr,
    unsigned* __restrict__ z, float* __restrict__ outself, int n)
{
    int i = blockIdx.x * blockDim.x + threadIdx.x;
    if (i >= n) return;

    float al[FOUT], ar[FOUT];
#pragma unroll
    for (int j = 0; j < FOUT; ++j) { al[j] = 0.f; ar[j] = 0.f; }

    const float4* xr = (const float4*)(x + (size_t)i * FIN);
#pragma unroll
    for (int kk = 0; kk < FIN / 4; ++kk) {
        float4 xv = xr[kk];
        float v[4] = {xv.x, xv.y, xv.z, xv.w};
#pragma unroll
        for (int c = 0; c < 4; ++c) {
            int k = kk * 4 + c;
#pragma unroll
            for (int j = 0; j < FOUT; ++j) {
                al[j] = fmaf(v[c], Wl[k * FOUT + j], al[j]);   // uniform -> s_load
                ar[j] = fmaf(v[c], Wr[k * FOUT + j], ar[j]);
            }
        }
    }

    uint4 pk;
    pk.x = bf16r(al[0]) | (bf16r(al[1]) << 16);
    pk.y = bf16r(al[2]) | (bf16r(al[3]) << 16);
    pk.z = bf16r(al[4]) | (bf16r(al[5]) << 16);
    pk.w = bf16r(al[6]);
    ((uint4*)z)[i] = pk;

    float* o = outself + (size_t)i * FOUT;
#pragma unroll
    for (int j = 0; j < FOUT; ++j)
        o[j] = ar[j] + bl[j];
}

// ---------------------------------------------------------------------------
// Kernel 2: partition — REVERTED to the proven R0 atomic version (bisect:
// halve the suspect surface after two container failures; its atomic cost
// is only ~10us of a ~9.5us-visible kernel).
// ---------------------------------------------------------------------------
__global__ __launch_bounds__(PTH) void part_kernel(
    const int* __restrict__ eg, unsigned* __restrict__ part,
    unsigned short* __restrict__ offs)
{
    __shared__ unsigned st_cnt[NCTR];      // copy-major: [wave][bucket]
    __shared__ unsigned st_start[NCTR];
    __shared__ unsigned stage[EPB];
    __shared__ unsigned wsum[NCOPY];

    const int t    = threadIdx.x;
    const int e0   = (int)blockIdx.x * EPB;
    const int lane = t & 63;
    const int wv   = t >> 6;

    for (int b = t; b < NCTR; b += PTH) st_cnt[b] = 0;
    __syncthreads();

    // pass A: two dwordx4 edge loads + merged hist+rank on this wave's copy
    unsigned held[4], hcr[4];
#pragma unroll
    for (int q = 0; q < 4; ++q) hcr[q] = INVALID;
    if (t < EPB / 4) {
        uint4 S = *(const uint4*)(eg + e0 + 4 * t);        // 4 srcs
        uint4 D = *(const uint4*)(eg + NE + e0 + 4 * t);   // 4 dsts
        unsigned ss[4] = {S.x, S.y, S.z, S.w};
        unsigned dd[4] = {D.x, D.y, D.z, D.w};
#pragma unroll
        for (int q = 0; q < 4; ++q) {
            unsigned b = dd[q] >> BSH;
            unsigned cidx = (unsigned)wv * NBK + b;        // copy-major
            unsigned r = atomicAdd(&st_cnt[cidx], 1u);
            held[q] = ((dd[q] & 511u) << 17) | ss[q];      // ldst 9b | src 17b
            hcr[q]  = (cidx << 10) | r;                    // cidx 10b | r<800 10b
        }
    }
    __syncthreads();

    // scan: thread t<196 owns bucket t; sum its 4 wave-copies, then a
    // 196-entry shfl scan across 4 waves for bucket starts.
    unsigned c[4], p[4], tot = 0;
    if (t < NBK) {
#pragma unroll
        for (int w = 0; w < NCOPY; ++w) c[w] = st_cnt[w * NBK + t];
        p[0] = 0; p[1] = c[0]; p[2] = c[0] + c[1]; p[3] = p[2] + c[2];
        tot = p[3] + c[3];
    }
    unsigned inc = tot;
#pragma unroll
    for (int off = 1; off < 64; off <<= 1) {
        unsigned v = (unsigned)__shfl_up((int)inc, off, 64);
        if (lane >= off) inc += v;
    }
    if (lane == 63) wsum[wv] = inc;
    __syncthreads();
    if (t == 0) {
        unsigned run = 0;
#pragma unroll
        for (int w = 0; w < NCOPY; ++w) { unsigned tmp = wsum[w]; wsum[w] = run; run += tmp; }
    }
    __syncthreads();
    unsigned bstart = wsum[wv] + inc - tot;    // exclusive bucket start
    if (t < NBK) {
        offs[(size_t)blockIdx.x * ROWS + t] = (unsigned short)bstart;
#pragma unroll
        for (int w = 0; w < NCOPY; ++w) st_start[w * NBK + t] = bstart + p[w];
    }
    if (t == NBK) offs[(size_t)blockIdx.x * ROWS + NBK] = (unsigned short)EPB;
    __syncthreads();

    // pass B: place held edges into bucket-sorted stage
#pragma unroll
    for (int q = 0; q < 4; ++q) {
        if (hcr[q] != INVALID) {
            unsigned cidx = hcr[q] >> 10, r = hcr[q] & 0x3FFu;
            stage[st_start[cidx] + r] = held[q];
        }
    }
    __syncthreads();

    // pass C: linear region dump (uint4)
    const uint4* sg = (const uint4*)stage;
    uint4* pg = (uint4*)(part + (size_t)blockIdx.x * EPB);
    for (int j = t; j < EPB / 4; j += PTH) pg[j] = sg[j];
}

// ---------------------------------------------------------------------------
// Kernel 3: accumulate — counting sort with ballot-based hist+rank (0
// per-edge atomics; LDS atomics measured ~4.5cy/LANE across R1/R4/R6).
// Tail rewritten as a provably-bounded loop: wave-max tail length via
// shfl_xor reduction, uniform trip count, per-lane validity — no
// convergence-dependent control flow (R7's __any-while removed).
// ---------------------------------------------------------------------------
__global__ __launch_bounds__(ATH) void acc_kernel(
    const unsigned short* __restrict__ offs, const unsigned* __restrict__ part,
    const unsigned* __restrict__ zb, float* __restrict__ partial)
{
    __shared__ unsigned hist[8][512];  // per-wave node hist -> scatter bases
    __shared__ __align__(16) unsigned sstage[SCAP + 8];
    __shared__ unsigned ovf[2 * OVCAP];
    __shared__ unsigned novf;
    __shared__ unsigned wtot[8];

    const int t    = threadIdx.x;
    const int lane = t & 63;
    const int wv   = t >> 6;
    const int k    = blockIdx.x >> 2;      // bucket
    const int sp   = blockIdx.x & 3;       // split
    const unsigned long long lmlt = (1ull << lane) - 1ull;

#pragma unroll
    for (int w = 0; w < 8; ++w) hist[w][t] = 0;
    if (t == 0) novf = 0;
    __syncthreads();

    unsigned rbase = 0, len = 0;
    if (t < RPS) {
        unsigned r = (unsigned)(sp * RPS + t);
        unsigned o0 = offs[(size_t)r * ROWS + k];
        unsigned o1 = offs[(size_t)r * ROWS + k + 1];
        len   = o1 - o0;
        rbase = r * EPB + o0;
    }

    // ---- pass A: aligned-window vector read + ballot hist+rank ----
    unsigned sh = rbase & 3u;
    const uint4* p4 = (const uint4*)part;
    unsigned wbase = rbase >> 2;
    uint4 W0 = len ? p4[wbase]     : make_uint4(0, 0, 0, 0);
    uint4 W1 = len ? p4[wbase + 1] : make_uint4(0, 0, 0, 0);
    uint4 W2 = len ? p4[wbase + 2] : make_uint4(0, 0, 0, 0);
    unsigned win[WSLOT] = {W0.x, W0.y, W0.z, W0.w,
                           W1.x, W1.y, W1.z, W1.w,
                           W2.x, W2.y, W2.z, W2.w};
    unsigned F = min(len, WSLOT - sh);
    unsigned rkw[WSLOT];
    bool     vl[WSLOT];
#pragma unroll
    for (int q = 0; q < WSLOT; ++q) {
        unsigned uq = (unsigned)q;
        bool v = (uq >= sh) && (uq < sh + F);
        vl[q] = v;
        unsigned n = win[q] >> 17;
        unsigned long long m = matchmask<9>(n, v);       // node < 512 -> 9 bits
        unsigned rkr = __popcll(m & lmlt);
        unsigned cnr = __popcll(m);
        unsigned cur = v ? hist[wv][n] : 0u;
        if (v && rkr == 0) hist[wv][n] = cur + cnr;      // leader, plain RMW
        rkw[q] = cur + rkr;
    }
    // tail (len > window capacity; rare): uniform trip count = wave-max tail
    {
        unsigned tail = len - F;                     // >= 0 by construction
        unsigned tmax = tail;
#pragma unroll
        for (int off = 32; off >= 1; off >>= 1)
            tmax = max(tmax, (unsigned)__shfl_xor((int)tmax, off, 64));
        for (unsigned jj = 0; jj < tmax; ++jj) {     // wave-uniform bound <= EPB
            bool v = (jj < tail);
            unsigned e = v ? part[rbase + F + jj] : 0u;
            unsigned n = e >> 17;
            unsigned long long m = matchmask<9>(n, v);
            unsigned rkr = __popcll(m & lmlt);
            unsigned cnr = __popcll(m);
            unsigned cur = v ? hist[wv][n] : 0u;
            if (v && rkr == 0) hist[wv][n] = cur + cnr;
            if (v) {
                unsigned p = atomicAdd(&novf, 1u);   // ~4/block, negligible
                if (p < OVCAP) {
                    ovf[2 * p]     = ((unsigned)wv << 28) | (n << 16) | (cur + rkr);
                    ovf[2 * p + 1] = e & 0x1FFFFu;
                }
            }
        }
    }
    __syncthreads();

    // ---- scan: thread t owns node t; per-wave bases + padded block scan ----
    unsigned wbs[8], tot = 0;
#pragma unroll
    for (int w = 0; w < 8; ++w) { wbs[w] = tot; tot += hist[w][t]; }
    unsigned pcnt = (tot + 3u) & ~3u;
    unsigned inc = pcnt;
#pragma unroll
    for (int off = 1; off < 64; off <<= 1) {
        unsigned v = (unsigned)__shfl_up((int)inc, off, 64);
        if (lane >= off) inc += v;
    }
    if (lane == 63) wtot[t >> 6] = inc;
    __syncthreads();
    if (t == 0) {
        unsigned run = 0;
#pragma unroll
        for (int w = 0; w < 8; ++w) { unsigned tmp = wtot[w]; wtot[w] = run; run += tmp; }
    }
    __syncthreads();
    unsigned mybase = wtot[t >> 6] + inc - pcnt;
#pragma unroll
    for (int w = 0; w < 8; ++w) hist[w][t] = mybase + wbs[w];   // scatter bases
    __syncthreads();

    // ---- pass B: scatter from registers (+ overflow) node-sorted ----
#pragma unroll
    for (int q = 0; q < WSLOT; ++q) {
        if (vl[q]) {
            unsigned n = win[q] >> 17;
            unsigned pp = hist[wv][n] + rkw[q];
            if (pp < SCAP) sstage[pp] = win[q] & 0x1FFFFu;
        }
    }
    for (unsigned q = t; q < min(novf, (unsigned)OVCAP); q += ATH) {
        unsigned a = ovf[2 * q], src = ovf[2 * q + 1];
        unsigned pp = hist[a >> 28][(a >> 16) & 0x1FFu] + (a & 0xFFFFu);
        if (pp < SCAP) sstage[pp] = src;
    }
    __syncthreads();

    // ---- pass C: batched reduce of node t's run (R0-identical) ----
    unsigned deg = tot;
    uint4 C0 = *(const uint4*)&sstage[mybase];
    uint4 C1 = *(const uint4*)&sstage[mybase + 4];
    unsigned sv[8] = {C0.x, C0.y, C0.z, C0.w, C1.x, C1.y, C1.z, C1.w};

    float a0 = 0.f, a1 = 0.f, a2 = 0.f, a3 = 0.f, a4 = 0.f, a5 = 0.f, a6 = 0.f;
#pragma unroll
    for (int j = 0; j < 8; ++j) {
        unsigned src = ((unsigned)j < deg) ? sv[j] : 0u;
        float m = ((unsigned)j < deg) ? 1.0f : 0.0f;
        uint4 zr = ((const uint4*)zb)[src];
        a0 = fmaf(m, bflo(zr.x), a0); a1 = fmaf(m, bfhi(zr.x), a1);
        a2 = fmaf(m, bflo(zr.y), a2); a3 = fmaf(m, bfhi(zr.y), a3);
        a4 = fmaf(m, bflo(zr.z), a4); a5 = fmaf(m, bfhi(zr.z), a5);
        a6 = fmaf(m, bflo(zr.w), a6);
    }
    for (unsigned j = 8; j < deg; ++j) {   // tail
        unsigned pp = mybase + j;
        if (pp >= SCAP) break;
        uint4 zr = ((const uint4*)zb)[sstage[pp]];
        a0 += bflo(zr.x); a1 += bfhi(zr.x);
        a2 += bflo(zr.y); a3 += bfhi(zr.y);
        a4 += bflo(zr.z); a5 += bfhi(zr.z);
        a6 += bflo(zr.w);
    }

    float* pp = partial + ((size_t)blockIdx.x * 512 + t) * 8;
    *(float4*)(pp)     = make_float4(a0, a1, a2, a3);
    *(float4*)(pp + 4) = make_float4(a4, a5, a6, (float)deg);
}

// ---------------------------------------------------------------------------
// Kernel 4: merge 4 split partials + mean + self + relu (unchanged).
// ---------------------------------------------------------------------------
__global__ __launch_bounds__(256) void merge_kernel(
    const float* __restrict__ partial, float* __restrict__ out, int n)
{
    int i = blockIdx.x * blockDim.x + threadIdx.x;
    if (i >= n) return;
    int k = i >> BSH;
    int node = i & 511;

    float s0 = 0.f, s1 = 0.f, s2 = 0.f, s3 = 0.f, s4 = 0.f, s5 = 0.f, s6 = 0.f, cn = 0.f;
#pragma unroll
    for (int s = 0; s < SPLIT; ++s) {
        const float4* p = (const float4*)(partial + ((size_t)(k * SPLIT + s) * 512 + node) * 8);
        float4 a = p[0], b = p[1];
        s0 += a.x; s1 += a.y; s2 += a.z; s3 += a.w;
        s4 += b.x; s5 += b.y; s6 += b.z; cn += b.w;
    }
    float r = 1.0f / fmaxf(cn, 1.0f);
    float* o = out + (size_t)i * FOUT;
    o[0] = fmaxf(fmaf(s0, r, o[0]), 0.f);
    o[1] = fmaxf(fmaf(s1, r, o[1]), 0.f);
    o[2] = fmaxf(fmaf(s2, r, o[2]), 0.f);
    o[3] = fmaxf(fmaf(s3, r, o[3]), 0.f);
    o[4] = fmaxf(fmaf(s4, r, o[4]), 0.f);
    o[5] = fmaxf(fmaf(s5, r, o[5]), 0.f);
    o[6] = fmaxf(fmaf(s6, r, o[6]), 0.f);
}

extern "C" void kernel_launch(void* const* d_in, const int* in_sizes, int n_in,
                              void* d_out, int out_size, void* d_ws, size_t ws_size,
                              hipStream_t stream) {
    const float* x   = (const float*)d_in[0];
    const int*   edg = (const int*)d_in[1];    // harness passes integers as int32
    const float* Wl  = (const float*)d_in[2];
    const float* bl  = (const float*)d_in[3];
    const float* Wr  = (const float*)d_in[4];
    float* out = (float*)d_out;

    // ws: z 1.6 MB | part 6.4 MB (+64B window slack) | offs 0.8 MB | partial 12.9 MB
    unsigned*       z       = (unsigned*)d_ws;                            // [NN*4]
    unsigned*       part    = z + (size_t)NN * 4;                         // [NE + 16]
    unsigned short* offs    = (unsigned short*)(part + (size_t)NE + 16); // [PBLK*ROWS]
    float*          partial = (float*)(offs + (size_t)PBLK * ROWS);      // [NTASK*512*8]

    proj_kernel<<<PROJB, 256, 0, stream>>>(x, Wl, bl, Wr, z, out, NN);
    part_kernel<<<PBLK, PTH, 0, stream>>>(edg, part, offs);
    acc_kernel<<<NTASK, ATH, 0, stream>>>(offs, part, z, partial);
    merge_kernel<<<(NN + 255) / 256, 256, 0, stream>>>(partial, out, NN);
}

// Round 10
// 125.193 us; speedup vs baseline: 1.5709x; 1.0381x over previous
//
#include <hip/hip_runtime.h>

#define NN 100000
#define NE 1600000
#define FIN 64
#define FOUT 7

#define BSH 9                        // bucket = dst >> 9 (512 nodes)
#define NBK 196                      // ceil(100000/512)
#define PBLK 2000                    // partition blocks (2000*800 = NE exact)
#define PTH  256
#define EPB  800                     // edges per partition region
#define NCOPY 4                      // per-wave counter copies (4 waves)
#define NCTR (NBK * NCOPY)           // 784
#define ROWS 200                     // offs row stride in u16 (197 used)
#define SPLIT 4                      // acc blocks per bucket
#define NTASK (NBK * SPLIT)          // 784
#define RPS (PBLK / SPLIT)           // 500 regions per acc task
#define ATH 512
#define WSLOT 12                     // aligned uint4 window: 3 x dwordx4
#define NSLOT 8                      // z slots per node (Poisson(4): P(deg>8)~2%)
#define OVCAP 256                    // LDS overflow pairs (expect ~25/task)
#define PROJB 391
#define INVALID 0xFFFFFFFFu

__device__ __forceinline__ unsigned bf16r(float f) {   // round-to-nearest-even
    unsigned u = __float_as_uint(f);
    return (u + 0x7fffu + ((u >> 16) & 1u)) >> 16;
}
__device__ __forceinline__ float bflo(unsigned u) { return __uint_as_float(u << 16); }
__device__ __forceinline__ float bfhi(unsigned u) { return __uint_as_float(u & 0xffff0000u); }

// ---------------------------------------------------------------------------
// Kernel 1: per-node projections (original fast version, unchanged).
// ---------------------------------------------------------------------------
__global__ __launch_bounds__(256) void proj_kernel(
    const float* __restrict__ x, const float* __restrict__ Wl,
    const float* __restrict__ bl, const float* __restrict__ Wr,
    unsigned* __restrict__ z, float* __restrict__ outself, int n)
{
    int i = blockIdx.x * blockDim.x + threadIdx.x;
    if (i >= n) return;

    float al[FOUT], ar[FOUT];
#pragma unroll
    for (int j = 0; j < FOUT; ++j) { al[j] = 0.f; ar[j] = 0.f; }

    const float4* xr = (const float4*)(x + (size_t)i * FIN);
#pragma unroll
    for (int kk = 0; kk < FIN / 4; ++kk) {
        float4 xv = xr[kk];
        float v[4] = {xv.x, xv.y, xv.z, xv.w};
#pragma unroll
        for (int c = 0; c < 4; ++c) {
            int k = kk * 4 + c;
#pragma unroll
            for (int j = 0; j < FOUT; ++j) {
                al[j] = fmaf(v[c], Wl[k * FOUT + j], al[j]);   // uniform -> s_load
                ar[j] = fmaf(v[c], Wr[k * FOUT + j], ar[j]);
            }
        }
    }

    uint4 pk;
    pk.x = bf16r(al[0]) | (bf16r(al[1]) << 16);
    pk.y = bf16r(al[2]) | (bf16r(al[3]) << 16);
    pk.z = bf16r(al[4]) | (bf16r(al[5]) << 16);
    pk.w = bf16r(al[6]);
    ((uint4*)z)[i] = pk;

    float* o = outself + (size_t)i * FOUT;
#pragma unroll
    for (int j = 0; j < FOUT; ++j)
        o[j] = ar[j] + bl[j];
}

// ---------------------------------------------------------------------------
// Kernel 2: partition (proven R0 atomic version, unchanged).
// ---------------------------------------------------------------------------
__global__ __launch_bounds__(PTH) void part_kernel(
    const int* __restrict__ eg, unsigned* __restrict__ part,
    unsigned short* __restrict__ offs)
{
    __shared__ unsigned st_cnt[NCTR];      // copy-major: [wave][bucket]
    __shared__ unsigned st_start[NCTR];
    __shared__ unsigned stage[EPB];
    __shared__ unsigned wsum[NCOPY];

    const int t    = threadIdx.x;
    const int e0   = (int)blockIdx.x * EPB;
    const int lane = t & 63;
    const int wv   = t >> 6;

    for (int b = t; b < NCTR; b += PTH) st_cnt[b] = 0;
    __syncthreads();

    // pass A: two dwordx4 edge loads + merged hist+rank on this wave's copy
    unsigned held[4], hcr[4];
#pragma unroll
    for (int q = 0; q < 4; ++q) hcr[q] = INVALID;
    if (t < EPB / 4) {
        uint4 S = *(const uint4*)(eg + e0 + 4 * t);        // 4 srcs
        uint4 D = *(const uint4*)(eg + NE + e0 + 4 * t);   // 4 dsts
        unsigned ss[4] = {S.x, S.y, S.z, S.w};
        unsigned dd[4] = {D.x, D.y, D.z, D.w};
#pragma unroll
        for (int q = 0; q < 4; ++q) {
            unsigned b = dd[q] >> BSH;
            unsigned cidx = (unsigned)wv * NBK + b;        // copy-major
            unsigned r = atomicAdd(&st_cnt[cidx], 1u);
            held[q] = ((dd[q] & 511u) << 17) | ss[q];      // ldst 9b | src 17b
            hcr[q]  = (cidx << 10) | r;                    // cidx 10b | r<800 10b
        }
    }
    __syncthreads();

    // scan: thread t<196 owns bucket t; sum its 4 wave-copies, then a
    // 196-entry shfl scan across 4 waves for bucket starts.
    unsigned c[4], p[4], tot = 0;
    if (t < NBK) {
#pragma unroll
        for (int w = 0; w < NCOPY; ++w) c[w] = st_cnt[w * NBK + t];
        p[0] = 0; p[1] = c[0]; p[2] = c[0] + c[1]; p[3] = p[2] + c[2];
        tot = p[3] + c[3];
    }
    unsigned inc = tot;
#pragma unroll
    for (int off = 1; off < 64; off <<= 1) {
        unsigned v = (unsigned)__shfl_up((int)inc, off, 64);
        if (lane >= off) inc += v;
    }
    if (lane == 63) wsum[wv] = inc;
    __syncthreads();
    if (t == 0) {
        unsigned run = 0;
#pragma unroll
        for (int w = 0; w < NCOPY; ++w) { unsigned tmp = wsum[w]; wsum[w] = run; run += tmp; }
    }
    __syncthreads();
    unsigned bstart = wsum[wv] + inc - tot;    // exclusive bucket start
    if (t < NBK) {
        offs[(size_t)blockIdx.x * ROWS + t] = (unsigned short)bstart;
#pragma unroll
        for (int w = 0; w < NCOPY; ++w) st_start[w * NBK + t] = bstart + p[w];
    }
    if (t == NBK) offs[(size_t)blockIdx.x * ROWS + NBK] = (unsigned short)EPB;
    __syncthreads();

    // pass B: place held edges into bucket-sorted stage
#pragma unroll
    for (int q = 0; q < 4; ++q) {
        if (hcr[q] != INVALID) {
            unsigned cidx = hcr[q] >> 10, r = hcr[q] & 0x3FFu;
            stage[st_start[cidx] + r] = held[q];
        }
    }
    __syncthreads();

    // pass C: linear region dump (uint4)
    const uint4* sg = (const uint4*)stage;
    uint4* pg = (uint4*)(part + (size_t)blockIdx.x * EPB);
    for (int j = t; j < EPB / 4; j += PTH) pg[j] = sg[j];
}

// ---------------------------------------------------------------------------
// Kernel 3: accumulate — SLOT-DIRECT: the rank atomic (the one irreducible
// ~4.5cy/lane cost, measured R1/R4/R6/R9) is reused as a unique slot index:
//   r = atomicAdd(&s_cnt[node],1); r<8 -> ds_write_b128 of raw bf16x8 z
//   into slots[r][node]; r>=8 (Poisson(4): ~2% nodes) -> LDS ovf list.
// Deletes the block scan, scatter stage, 2 barriers, and halves z-gathers
// (1/edge vs 8/thread). No slot zeroing needed: reduce reads j<deg only.
// No ballots / convergence-dependent control flow anywhere.
// ---------------------------------------------------------------------------
__global__ __launch_bounds__(ATH) void acc_kernel(
    const unsigned short* __restrict__ offs, const unsigned* __restrict__ part,
    const unsigned* __restrict__ zb, float* __restrict__ partial)
{
    __shared__ uint4    slots[NSLOT][512];   // 64 KB: bf16x8 z per (rank,node)
    __shared__ unsigned s_cnt[512];
    __shared__ unsigned ovf[2 * OVCAP];      // (node, src) pairs
    __shared__ unsigned novf;

    const int t  = threadIdx.x;
    const int k  = blockIdx.x >> 2;      // bucket
    const int sp = blockIdx.x & 3;       // split

    s_cnt[t] = 0;
    if (t == 0) novf = 0;
    __syncthreads();

    unsigned rbase = 0, len = 0;
    if (t < RPS) {
        unsigned r = (unsigned)(sp * RPS + t);
        unsigned o0 = offs[(size_t)r * ROWS + k];
        unsigned o1 = offs[(size_t)r * ROWS + k + 1];
        len   = o1 - o0;
        rbase = r * EPB + o0;
    }

    // ---- pass A: aligned-window vector read + rank-atomic slot write ----
    unsigned sh = rbase & 3u;
    const uint4* p4 = (const uint4*)part;
    unsigned wbase = rbase >> 2;
    uint4 W0 = len ? p4[wbase]     : make_uint4(0, 0, 0, 0);
    uint4 W1 = len ? p4[wbase + 1] : make_uint4(0, 0, 0, 0);
    uint4 W2 = len ? p4[wbase + 2] : make_uint4(0, 0, 0, 0);
    unsigned win[WSLOT] = {W0.x, W0.y, W0.z, W0.w,
                           W1.x, W1.y, W1.z, W1.w,
                           W2.x, W2.y, W2.z, W2.w};
    unsigned F = min(len, WSLOT - sh);
#pragma unroll
    for (int q = 0; q < WSLOT; ++q) {
        unsigned uq = (unsigned)q;
        if (uq >= sh && uq < sh + F) {
            unsigned e = win[q];
            unsigned node = e >> 17;
            unsigned src  = e & 0x1FFFFu;
            uint4 zr = ((const uint4*)zb)[src];            // L2-resident gather
            unsigned r = atomicAdd(&s_cnt[node], 1u);
            if (r < NSLOT) {
                slots[r][node] = zr;                       // plain ds_write_b128
            } else {
                unsigned p = atomicAdd(&novf, 1u);         // ~25/block
                if (p < OVCAP) { ovf[2 * p] = node; ovf[2 * p + 1] = src; }
            }
        }
    }
    for (unsigned j = F; j < len; ++j) {   // rare tail (len > window)
        unsigned e = part[rbase + j];
        unsigned node = e >> 17;
        unsigned src  = e & 0x1FFFFu;
        uint4 zr = ((const uint4*)zb)[src];
        unsigned r = atomicAdd(&s_cnt[node], 1u);
        if (r < NSLOT) {
            slots[r][node] = zr;
        } else {
            unsigned p = atomicAdd(&novf, 1u);
            if (p < OVCAP) { ovf[2 * p] = node; ovf[2 * p + 1] = src; }
        }
    }
    __syncthreads();

    // ---- reduce: thread t sums node t's slots (+ its overflow entries) ----
    unsigned deg = s_cnt[t];
    unsigned d = min(deg, (unsigned)NSLOT);
    float a0 = 0.f, a1 = 0.f, a2 = 0.f, a3 = 0.f, a4 = 0.f, a5 = 0.f, a6 = 0.f;
    for (unsigned j = 0; j < d; ++j) {
        uint4 zr = slots[j][t];
        a0 += bflo(zr.x); a1 += bfhi(zr.x);
        a2 += bflo(zr.y); a3 += bfhi(zr.y);
        a4 += bflo(zr.z); a5 += bfhi(zr.z);
        a6 += bflo(zr.w);
    }
    unsigned no = min(novf, (unsigned)OVCAP);
    for (unsigned q = 0; q < no; ++q) {            // broadcast reads, cheap
        if (ovf[2 * q] == (unsigned)t) {
            uint4 zr = ((const uint4*)zb)[ovf[2 * q + 1]];
            a0 += bflo(zr.x); a1 += bfhi(zr.x);
            a2 += bflo(zr.y); a3 += bfhi(zr.y);
            a4 += bflo(zr.z); a5 += bfhi(zr.z);
            a6 += bflo(zr.w);
        }
    }

    float* pp = partial + ((size_t)blockIdx.x * 512 + t) * 8;
    *(float4*)(pp)     = make_float4(a0, a1, a2, a3);
    *(float4*)(pp + 4) = make_float4(a4, a5, a6, (float)deg);
}

// ---------------------------------------------------------------------------
// Kernel 4: merge 4 split partials + mean + self + relu (unchanged).
// ---------------------------------------------------------------------------
__global__ __launch_bounds__(256) void merge_kernel(
    const float* __restrict__ partial, float* __restrict__ out, int n)
{
    int i = blockIdx.x * blockDim.x + threadIdx.x;
    if (i >= n) return;
    int k = i >> BSH;
    int node = i & 511;

    float s0 = 0.f, s1 = 0.f, s2 = 0.f, s3 = 0.f, s4 = 0.f, s5 = 0.f, s6 = 0.f, cn = 0.f;
#pragma unroll
    for (int s = 0; s < SPLIT; ++s) {
        const float4* p = (const float4*)(partial + ((size_t)(k * SPLIT + s) * 512 + node) * 8);
        float4 a = p[0], b = p[1];
        s0 += a.x; s1 += a.y; s2 += a.z; s3 += a.w;
        s4 += b.x; s5 += b.y; s6 += b.z; cn += b.w;
    }
    float r = 1.0f / fmaxf(cn, 1.0f);
    float* o = out + (size_t)i * FOUT;
    o[0] = fmaxf(fmaf(s0, r, o[0]), 0.f);
    o[1] = fmaxf(fmaf(s1, r, o[1]), 0.f);
    o[2] = fmaxf(fmaf(s2, r, o[2]), 0.f);
    o[3] = fmaxf(fmaf(s3, r, o[3]), 0.f);
    o[4] = fmaxf(fmaf(s4, r, o[4]), 0.f);
    o[5] = fmaxf(fmaf(s5, r, o[5]), 0.f);
    o[6] = fmaxf(fmaf(s6, r, o[6]), 0.f);
}

extern "C" void kernel_launch(void* const* d_in, const int* in_sizes, int n_in,
                              void* d_out, int out_size, void* d_ws, size_t ws_size,
                              hipStream_t stream) {
    const float* x   = (const float*)d_in[0];
    const int*   edg = (const int*)d_in[1];    // harness passes integers as int32
    const float* Wl  = (const float*)d_in[2];
    const float* bl  = (const float*)d_in[3];
    const float* Wr  = (const float*)d_in[4];
    float* out = (float*)d_out;

    // ws: z 1.6 MB | part 6.4 MB (+64B window slack) | offs 0.8 MB | partial 12.9 MB
    unsigned*       z       = (unsigned*)d_ws;                            // [NN*4]
    unsigned*       part    = z + (size_t)NN * 4;                         // [NE + 16]
    unsigned short* offs    = (unsigned short*)(part + (size_t)NE + 16); // [PBLK*ROWS]
    float*          partial = (float*)(offs + (size_t)PBLK * ROWS);      // [NTASK*512*8]

    proj_kernel<<<PROJB, 256, 0, stream>>>(x, Wl, bl, Wr, z, out, NN);
    part_kernel<<<PBLK, PTH, 0, stream>>>(edg, part, offs);
    acc_kernel<<<NTASK, ATH, 0, stream>>>(offs, part, z, partial);
    merge_kernel<<<(NN + 255) / 256, 256, 0, stream>>>(partial, out, NN);
}